// Round 16
// baseline (181.723 us; speedup 1.0000x reference)
//
#include <hip/hip_runtime.h>
#include <math.h>

#define RADIUS 0.05f

// ---------------- Spatial grid parameters ----------------
#define G 64
#define NC (G * G * G)          // 262144 cells
#define BOXLO -5.5f
#define BOXHI 5.5f
#define CELLH (11.0f / G)       // 0.171875 (exact in fp32)
#define INVH (G / 11.0f)

__device__ __forceinline__ int cell_coord(float v) {
    int c = (int)floorf((v - BOXLO) * INVH);
    return min(G - 1, max(0, c));
}

// ---------------- Grid build ----------------
__global__ void hist_kernel(const float* __restrict__ pcd, unsigned int* __restrict__ cnt, int N) {
    int j = blockIdx.x * 256 + threadIdx.x;
    if (j >= N) return;
    int cx = cell_coord(pcd[3 * j + 0]);
    int cy = cell_coord(pcd[3 * j + 1]);
    int cz = cell_coord(pcd[3 * j + 2]);
    atomicAdd(&cnt[(cx * G + cy) * G + cz], 1u);
}

// S1: 256-cell block scan via wave shuffles (2 syncs, not 16)
__global__ void scan1(const unsigned int* __restrict__ cnt, uint2* __restrict__ meta,
                      unsigned int* __restrict__ partials) {
    int i = blockIdx.x * 256 + threadIdx.x;
    unsigned int v = cnt[i];
    unsigned int s = v;  // inclusive scan within wave
#pragma unroll
    for (int off = 1; off < 64; off <<= 1) {
        unsigned int t = __shfl_up(s, off);
        if ((threadIdx.x & 63) >= off) s += t;
    }
    __shared__ unsigned int wsum[4];
    int wid = threadIdx.x >> 6;
    if ((threadIdx.x & 63) == 63) wsum[wid] = s;
    __syncthreads();
    unsigned int base = 0;
#pragma unroll
    for (int w = 0; w < 4; ++w)
        if (w < wid) base += wsum[w];
    meta[i] = make_uint2(base + s - v, v);  // exclusive, count
    if (threadIdx.x == 255) partials[blockIdx.x] = base + s;  // block total
}

// S2: single block, 1024 partials, shuffle scan (2 syncs)
__global__ void scan2(unsigned int* __restrict__ partials) {
    int t = threadIdx.x;
    unsigned int v = partials[t];
    unsigned int s = v;
#pragma unroll
    for (int off = 1; off < 64; off <<= 1) {
        unsigned int u = __shfl_up(s, off);
        if ((t & 63) >= off) s += u;
    }
    __shared__ unsigned int wsum[16];
    int wid = t >> 6;
    if ((t & 63) == 63) wsum[wid] = s;
    __syncthreads();
    unsigned int base = 0;
#pragma unroll
    for (int w = 0; w < 16; ++w)
        if (w < wid) base += wsum[w];
    partials[t] = base + s - v;  // exclusive
}

__global__ void scan3(uint2* __restrict__ meta, unsigned int* __restrict__ cursor,
                      const unsigned int* __restrict__ partials) {
    int i = blockIdx.x * 256 + threadIdx.x;
    unsigned int off = meta[i].x + partials[blockIdx.x];
    meta[i].x = off;
    cursor[i] = off;
}

__global__ void scatter_kernel(const float* __restrict__ pcd, unsigned int* __restrict__ cursor,
                               float4* __restrict__ pps, int N) {
    int j = blockIdx.x * 256 + threadIdx.x;
    if (j >= N) return;
    float p0 = pcd[3 * j + 0];
    float p1 = pcd[3 * j + 1];
    float p2 = pcd[3 * j + 2];
    int c = (cell_coord(p0) * G + cell_coord(p1)) * G + cell_coord(p2);
    unsigned int idx = atomicAdd(&cursor[c], 1u);
    pps[idx] = make_float4(-2.0f * p0, -2.0f * p1, -2.0f * p2,
                           p0 * p0 + p1 * p1 + p2 * p2);
}

// ---------------- Phase A: rings 0-1 (27 cells), batched meta loads ----------
// r14 counters (81us, VALUBusy 6.7%, Occ 8.4%): latency-chain kernel; ring-2
// divergence made 86% of waves walk 125 cells. Now: EXACTLY 27 cells per query
// (uniform, no divergence tax), all 27 meta loads issued up-front (1 latency
// instead of 27), fully unrolled so mc[] stays in registers (rule #20).
// best tracks e = |p|^2 - 2 x.p = d^2 - |x|^2; resolve iff best+|x|^2 <= thr^2,
// thr = CELLH - ov (unscanned points are >= CELLH - ov away). ~3.5% queue.
__global__ __launch_bounds__(256) void grid_query_a(const float* __restrict__ x,
                                                    const float* __restrict__ signs,
                                                    const uint2* __restrict__ meta,
                                                    const float4* __restrict__ pps,
                                                    float* __restrict__ out,
                                                    unsigned int* __restrict__ qcount,
                                                    unsigned int* __restrict__ queue, int M) {
    int q = blockIdx.x * 256 + threadIdx.x;
    if (q >= M) return;

    float qx = x[3 * q + 0], qy = x[3 * q + 1], qz = x[3 * q + 2];
    int cx = cell_coord(qx), cy = cell_coord(qy), cz = cell_coord(qz);
    float ov = fmaxf(fmaxf(fmaxf(BOXLO - qx, qx - BOXHI), fmaxf(BOXLO - qy, qy - BOXHI)),
                     fmaxf(fmaxf(BOXLO - qz, qz - BOXHI), 0.0f));
    float xs = fmaf(qx, qx, fmaf(qy, qy, qz * qz));

    // Batch-issue all 27 meta loads (independent gathers, one waitcnt).
    uint2 mc[27];
#pragma unroll
    for (int c = 0; c < 27; ++c) {
        int dxx = c / 9 - 1, dy = (c / 3) % 3 - 1, dz = c % 3 - 1;
        int X = cx + dxx, Y = cy + dy, Z = cz + dz;
        bool ok = ((unsigned)X < (unsigned)G) && ((unsigned)Y < (unsigned)G) &&
                  ((unsigned)Z < (unsigned)G);
        int idx = ok ? (X * G + Y) * G + Z : 0;
        uint2 m = meta[idx];
        mc[c].x = m.x;
        mc[c].y = ok ? m.y : 0u;
    }

    float best = INFINITY;
#pragma unroll
    for (int c = 0; c < 27; ++c) {
        const float4* p = pps + mc[c].x;
        unsigned n = mc[c].y;
        unsigned k = 0;
        for (; k + 2 <= n; k += 2) {
            float4 a = p[k], b = p[k + 1];
            float ea = fmaf(a.x, qx, fmaf(a.y, qy, fmaf(a.z, qz, a.w)));
            float eb = fmaf(b.x, qx, fmaf(b.y, qy, fmaf(b.z, qz, b.w)));
            best = fminf(best, fminf(ea, eb));
        }
        if (k < n) {
            float4 a = p[k];
            best = fminf(best, fmaf(a.x, qx, fmaf(a.y, qy, fmaf(a.z, qz, a.w))));
        }
    }

    float thr = CELLH - ov;
    if (thr > 0.0f && best + xs <= thr * thr) {
        float d = fmaxf(xs + best, 0.0f);
        out[q] = (sqrtf(d) - RADIUS) * signs[q];
    } else {
        unsigned int idx = atomicAdd(qcount, 1u);
        queue[idx] = (unsigned int)q;
    }
}

// ---------------- Phase B: one wave per queued query, full brute force --------
__global__ __launch_bounds__(256) void brute_queue(const float* __restrict__ x,
                                                   const float* __restrict__ signs,
                                                   const float4* __restrict__ pps,
                                                   const unsigned int* __restrict__ qcount,
                                                   const unsigned int* __restrict__ queue,
                                                   float* __restrict__ out, int N) {
    int lane = threadIdx.x & 63;
    int gwave = blockIdx.x * 4 + (threadIdx.x >> 6);
    int nwaves = gridDim.x * 4;
    unsigned int count = *qcount;

    for (unsigned int w = gwave; w < count; w += nwaves) {
        int q = (int)queue[w];  // wave-uniform
        float qx = x[3 * q + 0], qy = x[3 * q + 1], qz = x[3 * q + 2];
        float e0 = INFINITY, e1 = INFINITY, e2 = INFINITY, e3 = INFINITY;
        int j = lane;
        for (; j + 192 < N; j += 256) {
            float4 a = pps[j], b = pps[j + 64], c = pps[j + 128], d4 = pps[j + 192];
            e0 = fminf(e0, fmaf(a.x, qx, fmaf(a.y, qy, fmaf(a.z, qz, a.w))));
            e1 = fminf(e1, fmaf(b.x, qx, fmaf(b.y, qy, fmaf(b.z, qz, b.w))));
            e2 = fminf(e2, fmaf(c.x, qx, fmaf(c.y, qy, fmaf(c.z, qz, c.w))));
            e3 = fminf(e3, fmaf(d4.x, qx, fmaf(d4.y, qy, fmaf(d4.z, qz, d4.w))));
        }
        for (; j < N; j += 64) {
            float4 a = pps[j];
            e0 = fminf(e0, fmaf(a.x, qx, fmaf(a.y, qy, fmaf(a.z, qz, a.w))));
        }
        float e = fminf(fminf(e0, e1), fminf(e2, e3));
        e = fminf(e, __shfl_xor(e, 1));
        e = fminf(e, __shfl_xor(e, 2));
        e = fminf(e, __shfl_xor(e, 4));
        e = fminf(e, __shfl_xor(e, 8));
        e = fminf(e, __shfl_xor(e, 16));
        e = fminf(e, __shfl_xor(e, 32));
        if (lane == 0) {
            float xsq = fmaf(qx, qx, fmaf(qy, qy, qz * qz));
            float d = fmaxf(xsq + e, 0.0f);
            out[q] = (sqrtf(d) - RADIUS) * signs[q];
        }
    }
}

// ---------------- Brute-force fallback (r7, proven) ----------------
#define QPT 8
#define NSEG 64
typedef float f32x2 __attribute__((ext_vector_type(2)));

__global__ void init_best(unsigned int* __restrict__ best, int M) {
    int i = blockIdx.x * blockDim.x + threadIdx.x;
    if (i < M) best[i] = 0x7F800000u;
}

__global__ void pack_pcd(const float* __restrict__ pcd, float4* __restrict__ pp, int N) {
    int j = blockIdx.x * blockDim.x + threadIdx.x;
    if (j < N) {
        float p0 = pcd[3 * j], p1 = pcd[3 * j + 1], p2 = pcd[3 * j + 2];
        pp[j] = make_float4(-2.0f * p0, -2.0f * p1, -2.0f * p2,
                            p0 * p0 + p1 * p1 + p2 * p2);
    }
}

__global__ __launch_bounds__(256) void nn_min8(const float* __restrict__ x,
                                               const float4* __restrict__ pp,
                                               unsigned int* __restrict__ best,
                                               int M, int N, int seg_len, int qstride) {
    int t = blockIdx.x * 256 + threadIdx.x;
    int j0 = blockIdx.y * seg_len;
    int j1 = j0 + seg_len;
    if (j1 > N) j1 = N;

    int qid[QPT];
    f32x2 X0[4], X1[4], X2[4], E[4];
#pragma unroll
    for (int r = 0; r < 4; ++r) {
        int q0 = t + (2 * r) * qstride;
        int q1 = t + (2 * r + 1) * qstride;
        qid[2 * r] = q0;
        qid[2 * r + 1] = q1;
        bool ok0 = q0 < M, ok1 = q1 < M;
        int b0 = ok0 ? 3 * q0 : 0;
        int b1 = ok1 ? 3 * q1 : 0;
        X0[r] = (f32x2){ok0 ? x[b0 + 0] : 0.f, ok1 ? x[b1 + 0] : 0.f};
        X1[r] = (f32x2){ok0 ? x[b0 + 1] : 0.f, ok1 ? x[b1 + 1] : 0.f};
        X2[r] = (f32x2){ok0 ? x[b0 + 2] : 0.f, ok1 ? x[b1 + 2] : 0.f};
        E[r] = (f32x2){INFINITY, INFINITY};
    }

#pragma unroll 2
    for (int j = j0; j < j1; ++j) {
        float4 p = pp[j];
        f32x2 px2 = {p.x, p.x};
        f32x2 py2 = {p.y, p.y};
        f32x2 pz2 = {p.z, p.z};
        f32x2 w2 = {p.w, p.w};
#pragma unroll
        for (int r = 0; r < 4; ++r) {
            f32x2 d0 = __builtin_elementwise_fma(pz2, X2[r], w2);
            f32x2 d1 = __builtin_elementwise_fma(py2, X1[r], d0);
            f32x2 d2 = __builtin_elementwise_fma(px2, X0[r], d1);
            E[r].x = fminf(E[r].x, d2.x);
            E[r].y = fminf(E[r].y, d2.y);
        }
    }

#pragma unroll
    for (int r = 0; r < 4; ++r) {
        float xs0 = fmaf(X0[r].x, X0[r].x, fmaf(X1[r].x, X1[r].x, X2[r].x * X2[r].x));
        float xs1 = fmaf(X0[r].y, X0[r].y, fmaf(X1[r].y, X1[r].y, X2[r].y * X2[r].y));
        if (qid[2 * r] < M) {
            float d = fmaxf(xs0 + E[r].x, 0.0f);
            atomicMin(best + qid[2 * r], __float_as_uint(d));
        }
        if (qid[2 * r + 1] < M) {
            float d = fmaxf(xs1 + E[r].y, 0.0f);
            atomicMin(best + qid[2 * r + 1], __float_as_uint(d));
        }
    }
}

__global__ void finalize(unsigned int* __restrict__ bits, const float* __restrict__ signs,
                         float* __restrict__ out, int M) {
    int i = blockIdx.x * blockDim.x + threadIdx.x;
    if (i < M) {
        float d = __uint_as_float(bits[i]);
        out[i] = (sqrtf(d) - RADIUS) * signs[i];
    }
}

// ---------------- Launch ----------------
extern "C" void kernel_launch(void* const* d_in, const int* in_sizes, int n_in,
                              void* d_out, int out_size, void* d_ws, size_t ws_size,
                              hipStream_t stream) {
    const float* x = (const float*)d_in[0];
    const float* pcd = (const float*)d_in[1];
    const float* signs = (const float*)d_in[2];
    float* out = (float*)d_out;

    int M = in_sizes[0] / 3;
    int N = in_sizes[1] / 3;

    // ws carve: pps | meta | cnt(=cursor, reused after scan1) | partials | qcount | queue
    size_t need = (size_t)N * 16 + (size_t)NC * 8 + (size_t)NC * 4 + 4096 + 64 + (size_t)M * 4;

    if (ws_size >= need) {
        char* w = (char*)d_ws;
        float4* pps = (float4*)w;                 w += (size_t)N * 16;
        uint2* meta = (uint2*)w;                  w += (size_t)NC * 8;
        unsigned int* cnt = (unsigned int*)w;     w += (size_t)NC * 4;  // reused as cursor
        unsigned int* partials = (unsigned int*)w; w += 4096;
        unsigned int* qcount = (unsigned int*)w;  w += 64;
        unsigned int* queue = (unsigned int*)w;
        unsigned int* cursor = cnt;  // cnt dead after scan1; scan3 rewrites it as cursor

        hipMemsetAsync(cnt, 0, (size_t)NC * 4, stream);
        hipMemsetAsync(qcount, 0, 4, stream);
        hist_kernel<<<(N + 255) / 256, 256, 0, stream>>>(pcd, cnt, N);
        scan1<<<NC / 256, 256, 0, stream>>>(cnt, meta, partials);
        scan2<<<1, 1024, 0, stream>>>(partials);
        scan3<<<NC / 256, 256, 0, stream>>>(meta, cursor, partials);
        scatter_kernel<<<(N + 255) / 256, 256, 0, stream>>>(pcd, cursor, pps, N);
        grid_query_a<<<(M + 255) / 256, 256, 0, stream>>>(x, signs, meta, pps, out,
                                                          qcount, queue, M);
        brute_queue<<<512, 256, 0, stream>>>(x, signs, pps, qcount, queue, out, N);
    } else {
        // Fallback: proven brute-force path (r7)
        float4* pp = (float4*)d_ws;  // N * 16 B
        init_best<<<(M + 255) / 256, 256, 0, stream>>>((unsigned int*)d_out, M);
        pack_pcd<<<(N + 255) / 256, 256, 0, stream>>>(pcd, pp, N);
        int qstride = (M + QPT - 1) / QPT;
        int seg_len = (N + NSEG - 1) / NSEG;
        dim3 grid((qstride + 255) / 256, NSEG);
        nn_min8<<<grid, 256, 0, stream>>>(x, pp, (unsigned int*)d_out, M, N, seg_len, qstride);
        finalize<<<(M + 255) / 256, 256, 0, stream>>>((unsigned int*)d_out, signs, out, M);
    }
}

// Round 17
// 162.196 us; speedup vs baseline: 1.1204x; 1.1204x over previous
//
#include <hip/hip_runtime.h>
#include <math.h>

#define RADIUS 0.05f

// ---------------- Spatial grid parameters ----------------
#define G 64
#define NC (G * G * G)          // 262144 cells
#define BOXLO -5.5f
#define BOXHI 5.5f
#define CELLH (11.0f / G)       // 0.171875 (exact in fp32)
#define INVH (G / 11.0f)

__device__ __forceinline__ int cell_coord(float v) {
    int c = (int)floorf((v - BOXLO) * INVH);
    return min(G - 1, max(0, c));
}

// ---------------- Grid build ----------------
__global__ void hist_kernel(const float* __restrict__ pcd, unsigned int* __restrict__ cnt, int N) {
    int j = blockIdx.x * 256 + threadIdx.x;
    if (j >= N) return;
    int cx = cell_coord(pcd[3 * j + 0]);
    int cy = cell_coord(pcd[3 * j + 1]);
    int cz = cell_coord(pcd[3 * j + 2]);
    atomicAdd(&cnt[(cx * G + cy) * G + cz], 1u);
}

// S1: 256-cell block scan via wave shuffles
__global__ void scan1(const unsigned int* __restrict__ cnt, uint2* __restrict__ meta,
                      unsigned int* __restrict__ partials) {
    int i = blockIdx.x * 256 + threadIdx.x;
    unsigned int v = cnt[i];
    unsigned int s = v;
#pragma unroll
    for (int off = 1; off < 64; off <<= 1) {
        unsigned int t = __shfl_up(s, off);
        if ((threadIdx.x & 63) >= off) s += t;
    }
    __shared__ unsigned int wsum[4];
    int wid = threadIdx.x >> 6;
    if ((threadIdx.x & 63) == 63) wsum[wid] = s;
    __syncthreads();
    unsigned int base = 0;
#pragma unroll
    for (int w = 0; w < 4; ++w)
        if (w < wid) base += wsum[w];
    meta[i] = make_uint2(base + s - v, v);
    if (threadIdx.x == 255) partials[blockIdx.x] = base + s;
}

// S2: single block, 1024 partials
__global__ void scan2(unsigned int* __restrict__ partials) {
    int t = threadIdx.x;
    unsigned int v = partials[t];
    unsigned int s = v;
#pragma unroll
    for (int off = 1; off < 64; off <<= 1) {
        unsigned int u = __shfl_up(s, off);
        if ((t & 63) >= off) s += u;
    }
    __shared__ unsigned int wsum[16];
    int wid = t >> 6;
    if ((t & 63) == 63) wsum[wid] = s;
    __syncthreads();
    unsigned int base = 0;
#pragma unroll
    for (int w = 0; w < 16; ++w)
        if (w < wid) base += wsum[w];
    partials[t] = base + s - v;
}

__global__ void scan3(uint2* __restrict__ meta, unsigned int* __restrict__ cursor,
                      const unsigned int* __restrict__ partials) {
    int i = blockIdx.x * 256 + threadIdx.x;
    unsigned int off = meta[i].x + partials[blockIdx.x];
    meta[i].x = off;
    cursor[i] = off;
}

__global__ void scatter_kernel(const float* __restrict__ pcd, unsigned int* __restrict__ cursor,
                               float4* __restrict__ pps, int N) {
    int j = blockIdx.x * 256 + threadIdx.x;
    if (j >= N) return;
    float p0 = pcd[3 * j + 0];
    float p1 = pcd[3 * j + 1];
    float p2 = pcd[3 * j + 2];
    int c = (cell_coord(p0) * G + cell_coord(p1)) * G + cell_coord(p2);
    unsigned int idx = atomicAdd(&cursor[c], 1u);
    pps[idx] = make_float4(-2.0f * p0, -2.0f * p1, -2.0f * p2,
                           p0 * p0 + p1 * p1 + p2 * p2);
}

// ---------------- Phase A: rings 0-1 (27 cells), batched meta loads ----------
// EXACT per-query threshold (replaces blanket CELLH-ov): with u_a = query
// offset in its cell along axis a, every UNSCANNED point (cell index diff >=2
// on some axis) satisfies dist >= min_a min(2h - u_a, h + u_a):
//   delta>=+2: p.a >= cell_lo + (c_a+2)h = q_a + (2h - u_a)  (clamped-high pts
//     are beyond the box -> even farther);
//   delta<=-2: p.a <= cell_lo + (c_a-1)h = q_a - (u_a + h)   (clamped-low pts
//     have even smaller coords). Queries outside the box give thr<=0 -> queued.
// best tracks e = |p|^2 - 2 x.p = d^2 - |x|^2; resolve iff best+|x|^2 <= thr^2.
__global__ __launch_bounds__(256) void grid_query_a(const float* __restrict__ x,
                                                    const float* __restrict__ signs,
                                                    const uint2* __restrict__ meta,
                                                    const float4* __restrict__ pps,
                                                    float* __restrict__ out,
                                                    unsigned int* __restrict__ qcount,
                                                    unsigned int* __restrict__ queue, int M) {
    int q = blockIdx.x * 256 + threadIdx.x;
    if (q >= M) return;

    float qx = x[3 * q + 0], qy = x[3 * q + 1], qz = x[3 * q + 2];
    int cx = cell_coord(qx), cy = cell_coord(qy), cz = cell_coord(qz);
    float ux = qx - (BOXLO + cx * CELLH);
    float uy = qy - (BOXLO + cy * CELLH);
    float uz = qz - (BOXLO + cz * CELLH);
    float thr = fminf(fminf(2.0f * CELLH - ux, CELLH + ux),
                fminf(fminf(2.0f * CELLH - uy, CELLH + uy),
                      fminf(2.0f * CELLH - uz, CELLH + uz)));
    float xs = fmaf(qx, qx, fmaf(qy, qy, qz * qz));

    // Batch-issue all 27 meta loads (independent gathers, one waitcnt).
    uint2 mc[27];
#pragma unroll
    for (int c = 0; c < 27; ++c) {
        int dxx = c / 9 - 1, dy = (c / 3) % 3 - 1, dz = c % 3 - 1;
        int X = cx + dxx, Y = cy + dy, Z = cz + dz;
        bool ok = ((unsigned)X < (unsigned)G) && ((unsigned)Y < (unsigned)G) &&
                  ((unsigned)Z < (unsigned)G);
        int idx = ok ? (X * G + Y) * G + Z : 0;
        uint2 m = meta[idx];
        mc[c].x = m.x;
        mc[c].y = ok ? m.y : 0u;
    }

    float best = INFINITY;
#pragma unroll
    for (int c = 0; c < 27; ++c) {
        const float4* p = pps + mc[c].x;
        unsigned n = mc[c].y;
        unsigned k = 0;
        for (; k + 2 <= n; k += 2) {
            float4 a = p[k], b = p[k + 1];
            float ea = fmaf(a.x, qx, fmaf(a.y, qy, fmaf(a.z, qz, a.w)));
            float eb = fmaf(b.x, qx, fmaf(b.y, qy, fmaf(b.z, qz, b.w)));
            best = fminf(best, fminf(ea, eb));
        }
        if (k < n) {
            float4 a = p[k];
            best = fminf(best, fmaf(a.x, qx, fmaf(a.y, qy, fmaf(a.z, qz, a.w))));
        }
    }

    if (thr > 0.0f && best + xs <= thr * thr) {
        float d = fmaxf(xs + best, 0.0f);
        out[q] = (sqrtf(d) - RADIUS) * signs[q];
    } else {
        unsigned int idx = atomicAdd(qcount, 1u);
        queue[idx] = (unsigned int)q;
    }
}

// ---------------- Phase B: one BLOCK per queued query ------------------------
// r16 counters (74us, VALUBusy 23%, Occ 17.7%): wave-per-query was a 128-step
// cross-XCD latency chain with 2 waves/SIMD. Block-per-query: 256 threads split
// N -> 32 unrolled iterations/lane (4x shorter chain) and ~12 blocks/CU of TLP.
__global__ __launch_bounds__(256) void brute_block(const float* __restrict__ x,
                                                   const float* __restrict__ signs,
                                                   const float4* __restrict__ pps,
                                                   const unsigned int* __restrict__ qcount,
                                                   const unsigned int* __restrict__ queue,
                                                   float* __restrict__ out, int N) {
    __shared__ float sE[4];
    int lane = threadIdx.x & 63;
    int wid = threadIdx.x >> 6;
    unsigned int count = *qcount;

    for (unsigned int w = blockIdx.x; w < count; w += gridDim.x) {
        int q = (int)queue[w];  // block-uniform
        float qx = x[3 * q + 0], qy = x[3 * q + 1], qz = x[3 * q + 2];
        float e0 = INFINITY, e1 = INFINITY, e2 = INFINITY, e3 = INFINITY;
        int j = threadIdx.x;
        for (; j + 768 < N; j += 1024) {  // 128 pts/thread, 4-unrolled = 32 iters
            float4 a = pps[j], b = pps[j + 256], c = pps[j + 512], d4 = pps[j + 768];
            e0 = fminf(e0, fmaf(a.x, qx, fmaf(a.y, qy, fmaf(a.z, qz, a.w))));
            e1 = fminf(e1, fmaf(b.x, qx, fmaf(b.y, qy, fmaf(b.z, qz, b.w))));
            e2 = fminf(e2, fmaf(c.x, qx, fmaf(c.y, qy, fmaf(c.z, qz, c.w))));
            e3 = fminf(e3, fmaf(d4.x, qx, fmaf(d4.y, qy, fmaf(d4.z, qz, d4.w))));
        }
        for (; j < N; j += 256) {
            float4 a = pps[j];
            e0 = fminf(e0, fmaf(a.x, qx, fmaf(a.y, qy, fmaf(a.z, qz, a.w))));
        }
        float e = fminf(fminf(e0, e1), fminf(e2, e3));
        e = fminf(e, __shfl_xor(e, 1));
        e = fminf(e, __shfl_xor(e, 2));
        e = fminf(e, __shfl_xor(e, 4));
        e = fminf(e, __shfl_xor(e, 8));
        e = fminf(e, __shfl_xor(e, 16));
        e = fminf(e, __shfl_xor(e, 32));
        if (lane == 0) sE[wid] = e;
        __syncthreads();
        if (threadIdx.x == 0) {
            float em = fminf(fminf(sE[0], sE[1]), fminf(sE[2], sE[3]));
            float xsq = fmaf(qx, qx, fmaf(qy, qy, qz * qz));
            float d = fmaxf(xsq + em, 0.0f);
            out[q] = (sqrtf(d) - RADIUS) * signs[q];
        }
        __syncthreads();  // protect sE before next grid-stride query
    }
}

// ---------------- Brute-force fallback (r7, proven) ----------------
#define QPT 8
#define NSEG 64
typedef float f32x2 __attribute__((ext_vector_type(2)));

__global__ void init_best(unsigned int* __restrict__ best, int M) {
    int i = blockIdx.x * blockDim.x + threadIdx.x;
    if (i < M) best[i] = 0x7F800000u;
}

__global__ void pack_pcd(const float* __restrict__ pcd, float4* __restrict__ pp, int N) {
    int j = blockIdx.x * blockDim.x + threadIdx.x;
    if (j < N) {
        float p0 = pcd[3 * j], p1 = pcd[3 * j + 1], p2 = pcd[3 * j + 2];
        pp[j] = make_float4(-2.0f * p0, -2.0f * p1, -2.0f * p2,
                            p0 * p0 + p1 * p1 + p2 * p2);
    }
}

__global__ __launch_bounds__(256) void nn_min8(const float* __restrict__ x,
                                               const float4* __restrict__ pp,
                                               unsigned int* __restrict__ best,
                                               int M, int N, int seg_len, int qstride) {
    int t = blockIdx.x * 256 + threadIdx.x;
    int j0 = blockIdx.y * seg_len;
    int j1 = j0 + seg_len;
    if (j1 > N) j1 = N;

    int qid[QPT];
    f32x2 X0[4], X1[4], X2[4], E[4];
#pragma unroll
    for (int r = 0; r < 4; ++r) {
        int q0 = t + (2 * r) * qstride;
        int q1 = t + (2 * r + 1) * qstride;
        qid[2 * r] = q0;
        qid[2 * r + 1] = q1;
        bool ok0 = q0 < M, ok1 = q1 < M;
        int b0 = ok0 ? 3 * q0 : 0;
        int b1 = ok1 ? 3 * q1 : 0;
        X0[r] = (f32x2){ok0 ? x[b0 + 0] : 0.f, ok1 ? x[b1 + 0] : 0.f};
        X1[r] = (f32x2){ok0 ? x[b0 + 1] : 0.f, ok1 ? x[b1 + 1] : 0.f};
        X2[r] = (f32x2){ok0 ? x[b0 + 2] : 0.f, ok1 ? x[b1 + 2] : 0.f};
        E[r] = (f32x2){INFINITY, INFINITY};
    }

#pragma unroll 2
    for (int j = j0; j < j1; ++j) {
        float4 p = pp[j];
        f32x2 px2 = {p.x, p.x};
        f32x2 py2 = {p.y, p.y};
        f32x2 pz2 = {p.z, p.z};
        f32x2 w2 = {p.w, p.w};
#pragma unroll
        for (int r = 0; r < 4; ++r) {
            f32x2 d0 = __builtin_elementwise_fma(pz2, X2[r], w2);
            f32x2 d1 = __builtin_elementwise_fma(py2, X1[r], d0);
            f32x2 d2 = __builtin_elementwise_fma(px2, X0[r], d1);
            E[r].x = fminf(E[r].x, d2.x);
            E[r].y = fminf(E[r].y, d2.y);
        }
    }

#pragma unroll
    for (int r = 0; r < 4; ++r) {
        float xs0 = fmaf(X0[r].x, X0[r].x, fmaf(X1[r].x, X1[r].x, X2[r].x * X2[r].x));
        float xs1 = fmaf(X0[r].y, X0[r].y, fmaf(X1[r].y, X1[r].y, X2[r].y * X2[r].y));
        if (qid[2 * r] < M) {
            float d = fmaxf(xs0 + E[r].x, 0.0f);
            atomicMin(best + qid[2 * r], __float_as_uint(d));
        }
        if (qid[2 * r + 1] < M) {
            float d = fmaxf(xs1 + E[r].y, 0.0f);
            atomicMin(best + qid[2 * r + 1], __float_as_uint(d));
        }
    }
}

__global__ void finalize(unsigned int* __restrict__ bits, const float* __restrict__ signs,
                         float* __restrict__ out, int M) {
    int i = blockIdx.x * blockDim.x + threadIdx.x;
    if (i < M) {
        float d = __uint_as_float(bits[i]);
        out[i] = (sqrtf(d) - RADIUS) * signs[i];
    }
}

// ---------------- Launch ----------------
extern "C" void kernel_launch(void* const* d_in, const int* in_sizes, int n_in,
                              void* d_out, int out_size, void* d_ws, size_t ws_size,
                              hipStream_t stream) {
    const float* x = (const float*)d_in[0];
    const float* pcd = (const float*)d_in[1];
    const float* signs = (const float*)d_in[2];
    float* out = (float*)d_out;

    int M = in_sizes[0] / 3;
    int N = in_sizes[1] / 3;

    // ws carve: pps | meta | cnt(=cursor, reused after scan1) | partials | qcount | queue
    size_t need = (size_t)N * 16 + (size_t)NC * 8 + (size_t)NC * 4 + 4096 + 64 + (size_t)M * 4;

    if (ws_size >= need) {
        char* w = (char*)d_ws;
        float4* pps = (float4*)w;                 w += (size_t)N * 16;
        uint2* meta = (uint2*)w;                  w += (size_t)NC * 8;
        unsigned int* cnt = (unsigned int*)w;     w += (size_t)NC * 4;  // reused as cursor
        unsigned int* partials = (unsigned int*)w; w += 4096;
        unsigned int* qcount = (unsigned int*)w;  w += 64;
        unsigned int* queue = (unsigned int*)w;
        unsigned int* cursor = cnt;  // cnt dead after scan1; scan3 rewrites it as cursor

        hipMemsetAsync(cnt, 0, (size_t)NC * 4, stream);
        hipMemsetAsync(qcount, 0, 4, stream);
        hist_kernel<<<(N + 255) / 256, 256, 0, stream>>>(pcd, cnt, N);
        scan1<<<NC / 256, 256, 0, stream>>>(cnt, meta, partials);
        scan2<<<1, 1024, 0, stream>>>(partials);
        scan3<<<NC / 256, 256, 0, stream>>>(meta, cursor, partials);
        scatter_kernel<<<(N + 255) / 256, 256, 0, stream>>>(pcd, cursor, pps, N);
        grid_query_a<<<(M + 255) / 256, 256, 0, stream>>>(x, signs, meta, pps, out,
                                                          qcount, queue, M);
        brute_block<<<2048, 256, 0, stream>>>(x, signs, pps, qcount, queue, out, N);
    } else {
        // Fallback: proven brute-force path (r7)
        float4* pp = (float4*)d_ws;  // N * 16 B
        init_best<<<(M + 255) / 256, 256, 0, stream>>>((unsigned int*)d_out, M);
        pack_pcd<<<(N + 255) / 256, 256, 0, stream>>>(pcd, pp, N);
        int qstride = (M + QPT - 1) / QPT;
        int seg_len = (N + NSEG - 1) / NSEG;
        dim3 grid((qstride + 255) / 256, NSEG);
        nn_min8<<<grid, 256, 0, stream>>>(x, pp, (unsigned int*)d_out, M, N, seg_len, qstride);
        finalize<<<(M + 255) / 256, 256, 0, stream>>>((unsigned int*)d_out, signs, out, M);
    }
}